// Round 1
// baseline (128.532 us; speedup 1.0000x reference)
//
#include <hip/hip_runtime.h>
#include <hip/hip_bf16.h>

// Problem constants (B,S,H,P) = (512, 256, 768, 32)
#define B_  512
#define S_  256
#define H_  768
#define P_  32
#define K1_ (3*H_)   // 2304
#define K2_ (2*H_)   // 1536
#define N_  H_       // 768
#define M_  B_       // 512

// ---------------------------------------------------------------------------
// Kernel 1: masked mean-pool over gathered positions + concat into GEMM inputs
//   combined (B x 3H) = [pooled_proc | proc_sent | phys_sent]
//   micro_in (B x 2H) = [pooled_micro | micro_sent]
// One block per batch, 192 threads = one float4 column each (H/4 = 192).
// ---------------------------------------------------------------------------
__global__ __launch_bounds__(192) void pool_concat_kernel(
    const float* __restrict__ phys, const float* __restrict__ proc,
    const float* __restrict__ micro, const int* __restrict__ pos,
    float* __restrict__ combined, float* __restrict__ micro_in) {
  const int b = blockIdx.x;
  const int t = threadIdx.x;  // 0..191
  __shared__ int sp[P_];
  __shared__ float sinv;
  if (t < P_) sp[t] = pos[b * P_ + t];
  __syncthreads();
  if (t == 0) {
    int c = 0;
    for (int i = 0; i < P_; ++i) c += (sp[i] != -1);
    sinv = 1.0f / (float)c;  // drop[:,0]==False guarantees c >= 1
  }
  __syncthreads();

  const int H4 = H_ / 4;  // 192
  const float4* procb  = (const float4*)(proc  + (size_t)b * S_ * H_);
  const float4* microb = (const float4*)(micro + (size_t)b * S_ * H_);
  const float4* physb  = (const float4*)(phys  + (size_t)b * S_ * H_);

  float4 sp_sum = make_float4(0.f, 0.f, 0.f, 0.f);
  float4 sm_sum = make_float4(0.f, 0.f, 0.f, 0.f);
  for (int i = 0; i < P_; ++i) {
    int p = sp[i];           // wave-uniform
    if (p != -1) {
      float4 vp = procb[(size_t)p * H4 + t];
      float4 vm = microb[(size_t)p * H4 + t];
      sp_sum.x += vp.x; sp_sum.y += vp.y; sp_sum.z += vp.z; sp_sum.w += vp.w;
      sm_sum.x += vm.x; sm_sum.y += vm.y; sm_sum.z += vm.z; sm_sum.w += vm.w;
    }
  }
  const float inv = sinv;
  float4 pooled_p = make_float4(sp_sum.x*inv, sp_sum.y*inv, sp_sum.z*inv, sp_sum.w*inv);
  float4 pooled_m = make_float4(sm_sum.x*inv, sm_sum.y*inv, sm_sum.z*inv, sm_sum.w*inv);
  float4 sent_p  = procb[t];   // row 0
  float4 sent_m  = microb[t];
  float4 sent_ph = physb[t];

  float4* crow = (float4*)(combined + (size_t)b * K1_);
  crow[t]          = pooled_p;
  crow[H4 + t]     = sent_p;
  crow[2*H4 + t]   = sent_ph;
  float4* mrow = (float4*)(micro_in + (size_t)b * K2_);
  mrow[t]          = pooled_m;
  mrow[H4 + t]     = sent_m;
}

// ---------------------------------------------------------------------------
// Kernel 2: fused dual NT GEMM (fp32 vector ALU):
//   out[0:M*N)      = combined (MxK1) . W1^T (K1xN) + b1
//   out[M*N:2*M*N)  = micro_in (MxK2) . W2^T (K2xN) + b2
// BM=BN=64, BK=32, 256 threads, 4x4 outputs/thread, transposed padded LDS.
// ---------------------------------------------------------------------------
#define BM 64
#define BN 64
#define BK 32
#define PAD 68  // 64 + 4 (keeps float4 alignment, breaks bank aliasing)

__global__ __launch_bounds__(256) void gemm_dual_kernel(
    const float* __restrict__ combined, const float* __restrict__ micro_in,
    const float* __restrict__ W1, const float* __restrict__ b1,
    const float* __restrict__ W2, const float* __restrict__ b2,
    float* __restrict__ out) {
  __shared__ float As[BK][PAD];  // [k][m]
  __shared__ float Bs[BK][PAD];  // [k][n]

  int bid = blockIdx.x;
  const int nb1 = (M_ / BM) * (N_ / BN);  // 96
  const float* A; const float* W; const float* bias; float* C; int K;
  if (bid < nb1) {
    A = combined; W = W1; bias = b1; C = out; K = K1_;
  } else {
    bid -= nb1;
    A = micro_in; W = W2; bias = b2; C = out + (size_t)M_ * N_; K = K2_;
  }
  const int bm = bid / (N_ / BN);
  const int bn = bid % (N_ / BN);
  const int m0 = bm * BM;
  const int n0 = bn * BN;

  const int tid = threadIdx.x;
  const int tx = tid & 15;   // 16 cols of 4
  const int ty = tid >> 4;   // 16 rows of 4

  float acc[4][4] = {};

  for (int kt = 0; kt < K; kt += BK) {
    // Stage 64x32 A-tile and 64x32 W-tile, transposed into LDS.
#pragma unroll
    for (int j = 0; j < 2; ++j) {
      int fidx = tid + j * 256;      // 0..511
      int row = fidx >> 3;           // 0..63
      int cg  = fidx & 7;            // float4 group along K
      float4 va = *(const float4*)(A + (size_t)(m0 + row) * K + kt + cg * 4);
      float4 vw = *(const float4*)(W + (size_t)(n0 + row) * K + kt + cg * 4);
      As[cg*4+0][row] = va.x; As[cg*4+1][row] = va.y;
      As[cg*4+2][row] = va.z; As[cg*4+3][row] = va.w;
      Bs[cg*4+0][row] = vw.x; Bs[cg*4+1][row] = vw.y;
      Bs[cg*4+2][row] = vw.z; Bs[cg*4+3][row] = vw.w;
    }
    __syncthreads();

#pragma unroll
    for (int k = 0; k < BK; ++k) {
      float4 a = *(const float4*)&As[k][ty * 4];
      float4 b = *(const float4*)&Bs[k][tx * 4];
      acc[0][0] += a.x * b.x; acc[0][1] += a.x * b.y;
      acc[0][2] += a.x * b.z; acc[0][3] += a.x * b.w;
      acc[1][0] += a.y * b.x; acc[1][1] += a.y * b.y;
      acc[1][2] += a.y * b.z; acc[1][3] += a.y * b.w;
      acc[2][0] += a.z * b.x; acc[2][1] += a.z * b.y;
      acc[2][2] += a.z * b.z; acc[2][3] += a.z * b.w;
      acc[3][0] += a.w * b.x; acc[3][1] += a.w * b.y;
      acc[3][2] += a.w * b.z; acc[3][3] += a.w * b.w;
    }
    __syncthreads();
  }

  // Epilogue: add bias, store (pre-normalization).
  float4 bv;
  bv.x = bias[n0 + tx*4 + 0];
  bv.y = bias[n0 + tx*4 + 1];
  bv.z = bias[n0 + tx*4 + 2];
  bv.w = bias[n0 + tx*4 + 3];
#pragma unroll
  for (int i = 0; i < 4; ++i) {
    float4 r;
    r.x = acc[i][0] + bv.x;
    r.y = acc[i][1] + bv.y;
    r.z = acc[i][2] + bv.z;
    r.w = acc[i][3] + bv.w;
    *(float4*)(C + (size_t)(m0 + ty*4 + i) * N_ + n0 + tx*4) = r;
  }
}

// ---------------------------------------------------------------------------
// Kernel 3: in-place row L2 normalization of out (2*B rows of 768).
// ---------------------------------------------------------------------------
__global__ __launch_bounds__(256) void norm_rows_kernel(float* __restrict__ out) {
  const int row = blockIdx.x;        // 0..1023
  float* p = out + (size_t)row * N_;
  const int t = threadIdx.x;         // 256 threads x 3 elems = 768
  float x0 = p[t];
  float x1 = p[t + 256];
  float x2 = p[t + 512];
  float s = x0*x0 + x1*x1 + x2*x2;
  // 64-lane wave reduce
#pragma unroll
  for (int off = 32; off > 0; off >>= 1) s += __shfl_down(s, off);
  __shared__ float ws[4];
  const int lane = t & 63, wid = t >> 6;
  if (lane == 0) ws[wid] = s;
  __syncthreads();
  float tot = ws[0] + ws[1] + ws[2] + ws[3];
  float n = sqrtf(tot);
  float inv = 1.0f / fmaxf(n, 1e-12f);
  p[t]       = x0 * inv;
  p[t + 256] = x1 * inv;
  p[t + 512] = x2 * inv;
}

// ---------------------------------------------------------------------------
extern "C" void kernel_launch(void* const* d_in, const int* in_sizes, int n_in,
                              void* d_out, int out_size, void* d_ws, size_t ws_size,
                              hipStream_t stream) {
  const float* phys  = (const float*)d_in[0];
  const float* proc  = (const float*)d_in[1];
  const float* micro = (const float*)d_in[2];
  const int*   pos   = (const int*)d_in[3];
  const float* W1    = (const float*)d_in[4];
  const float* b1    = (const float*)d_in[5];
  const float* W2    = (const float*)d_in[6];
  const float* b2    = (const float*)d_in[7];
  float* out = (float*)d_out;

  float* combined = (float*)d_ws;                       // 512*2304 floats
  float* micro_in = combined + (size_t)M_ * K1_;        // 512*1536 floats

  pool_concat_kernel<<<B_, 192, 0, stream>>>(phys, proc, micro, pos,
                                             combined, micro_in);
  const int nblocks = (M_/BM)*(N_/BN) * 2;  // 96 per GEMM, fused
  gemm_dual_kernel<<<nblocks, 256, 0, stream>>>(combined, micro_in,
                                                W1, b1, W2, b2, out);
  norm_rows_kernel<<<2 * B_, 256, 0, stream>>>(out);
}

// Round 2
// 50.979 us; speedup vs baseline: 2.5213x; 2.5213x over previous
//
#include <hip/hip_runtime.h>
#include <hip/hip_bf16.h>

// Problem constants (B,S,H,P) = (512, 256, 768, 32)
#define B_  512
#define S_  256
#define H_  768
#define P_  32
#define K1_ 2304   // 3H
#define K2_ 1536   // 2H
#define N_  768
#define M_  512
#define NK1 72     // K1/32
#define NK2 48     // K2/32
#define CVT_BLOCKS 128

typedef __attribute__((ext_vector_type(8))) short bf16x8v;
typedef __attribute__((ext_vector_type(4))) float f32x4v;

// Fragment buffers (bf16), MFMA 16x16x32 operand order:
//   frag[t16][k32][lane][8]  where lane = kg*16 + r  (r = row-in-16, kg = k-subgroup)
//   element (t, k):  t = t16*16 + r,  k = k32*32 + kg*8 + e   (e = 0..7)
// A-frag rows t = m (batch), W-frag rows t = n (output col); W is stored [n][k]
// which is exactly the B^T-input fragment layout (8 consecutive k per lane).
// Sizes (bf16 elems): A1f 32*NK1*512; A2f 32*NK2*512; W1f 48*NK1*512; W2f 48*NK2*512.

__device__ inline unsigned short bfb(float x) {
  __hip_bfloat16 h = __float2bfloat16(x);  // RNE
  return *reinterpret_cast<unsigned short*>(&h);
}

// store 4 consecutive-k bf16 values (k % 4 == 0) into frag layout, 8B store
__device__ inline void store4_frag(__hip_bfloat16* __restrict__ buf, int NK,
                                   int m, int k, float4 v) {
  int m16 = m >> 4, mr = m & 15, k32 = k >> 5, kg = (k >> 3) & 3, e = k & 7;
  size_t off = ((size_t)(m16 * NK + k32) * 64 + kg * 16 + mr) * 8 + e;
  ushort4 u;
  u.x = bfb(v.x); u.y = bfb(v.y); u.z = bfb(v.z); u.w = bfb(v.w);
  *reinterpret_cast<ushort4*>(buf + off) = u;
}

// ---------------------------------------------------------------------------
// Kernel 1 (fused): blocks [0,512): masked mean-pool + concat -> A-frag bf16
//                   blocks [512,512+CVT_BLOCKS): W1/W2 fp32 -> B-frag bf16
// ---------------------------------------------------------------------------
__global__ __launch_bounds__(192) void pool_cvt_kernel(
    const float* __restrict__ phys, const float* __restrict__ proc,
    const float* __restrict__ micro, const int* __restrict__ pos,
    const float* __restrict__ W1, const float* __restrict__ W2,
    __hip_bfloat16* __restrict__ A1f, __hip_bfloat16* __restrict__ A2f,
    __hip_bfloat16* __restrict__ W1f, __hip_bfloat16* __restrict__ W2f) {
  const int t = threadIdx.x;  // 0..191
  if (blockIdx.x < B_) {
    // ---- pooling part: one block per batch, thread t = float4 column ----
    const int b = blockIdx.x;
    __shared__ int sp[P_];
    __shared__ float sinv;
    if (t < P_) sp[t] = pos[b * P_ + t];
    __syncthreads();
    if (t == 0) {
      int c = 0;
      for (int i = 0; i < P_; ++i) c += (sp[i] != -1);
      sinv = 1.0f / (float)c;  // drop[:,0]==False guarantees c >= 1
    }
    __syncthreads();

    const int H4 = H_ / 4;  // 192
    const float4* procb  = (const float4*)(proc  + (size_t)b * S_ * H_);
    const float4* microb = (const float4*)(micro + (size_t)b * S_ * H_);
    const float4* physb  = (const float4*)(phys  + (size_t)b * S_ * H_);

    float4 spm = make_float4(0.f, 0.f, 0.f, 0.f);
    float4 smm = make_float4(0.f, 0.f, 0.f, 0.f);
    for (int i = 0; i < P_; ++i) {
      int p = sp[i];  // wave-uniform
      if (p != -1) {
        float4 vp = procb[(size_t)p * H4 + t];
        float4 vm = microb[(size_t)p * H4 + t];
        spm.x += vp.x; spm.y += vp.y; spm.z += vp.z; spm.w += vp.w;
        smm.x += vm.x; smm.y += vm.y; smm.z += vm.z; smm.w += vm.w;
      }
    }
    const float inv = sinv;
    float4 pooled_p = make_float4(spm.x*inv, spm.y*inv, spm.z*inv, spm.w*inv);
    float4 pooled_m = make_float4(smm.x*inv, smm.y*inv, smm.z*inv, smm.w*inv);
    float4 sent_p  = procb[t];
    float4 sent_m  = microb[t];
    float4 sent_ph = physb[t];

    const int k = t * 4;
    store4_frag(A1f, NK1, b, k,            pooled_p);
    store4_frag(A1f, NK1, b, k + H_,       sent_p);
    store4_frag(A1f, NK1, b, k + 2 * H_,   sent_ph);
    store4_frag(A2f, NK2, b, k,            pooled_m);
    store4_frag(A2f, NK2, b, k + H_,       sent_m);
  } else {
    // ---- W conversion part: grid-stride over 16B fragment groups ----
    const int NG1 = 48 * NK1 * 64;  // 221184
    const int NG2 = 48 * NK2 * 64;  // 147456
    int tid = (blockIdx.x - B_) * 192 + t;
    const int stride = CVT_BLOCKS * 192;
    for (int g = tid; g < NG1 + NG2; g += stride) {
      const float* W; __hip_bfloat16* Wf; int NK, K, gg;
      if (g < NG1) { W = W1; Wf = W1f; NK = NK1; K = K1_; gg = g; }
      else         { W = W2; Wf = W2f; NK = NK2; K = K2_; gg = g - NG1; }
      int lane = gg & 63;
      int rest = gg >> 6;
      int k32 = rest % NK;
      int n16 = rest / NK;
      int n = n16 * 16 + (lane & 15);
      int k = k32 * 32 + (lane >> 4) * 8;
      const float4* s = (const float4*)(W + (size_t)n * K + k);
      float4 v0 = s[0], v1 = s[1];
      ushort4 u0, u1;
      u0.x = bfb(v0.x); u0.y = bfb(v0.y); u0.z = bfb(v0.z); u0.w = bfb(v0.w);
      u1.x = bfb(v1.x); u1.y = bfb(v1.y); u1.z = bfb(v1.z); u1.w = bfb(v1.w);
      ushort4* d = reinterpret_cast<ushort4*>(Wf + (size_t)gg * 8);
      d[0] = u0; d[1] = u1;
    }
  }
}

// ---------------------------------------------------------------------------
// Kernel 2: dual bf16 MFMA GEMM, no LDS, no barriers.
// One wave per block; each wave owns a 32x32 output tile (2x2 fragments).
// ---------------------------------------------------------------------------
__global__ __launch_bounds__(64) void gemm_mfma_kernel(
    const __hip_bfloat16* __restrict__ A1f, const __hip_bfloat16* __restrict__ A2f,
    const __hip_bfloat16* __restrict__ W1f, const __hip_bfloat16* __restrict__ W2f,
    const float* __restrict__ b1, const float* __restrict__ b2,
    float* __restrict__ out) {
  int bid = blockIdx.x;
  const int TPG = (M_ / 32) * (N_ / 32);  // 16*24 = 384 tiles per GEMM
  const __hip_bfloat16 *Af, *Wf;
  const float* bias; float* C; int NK;
  if (bid < TPG) { Af = A1f; Wf = W1f; bias = b1; C = out;                    NK = NK1; }
  else { bid -= TPG; Af = A2f; Wf = W2f; bias = b2; C = out + (size_t)M_*N_;  NK = NK2; }
  const int mt = bid / (N_ / 32);   // 0..15
  const int nt = bid % (N_ / 32);   // 0..23
  const int lane = threadIdx.x;     // 0..63

  const bf16x8v* A0 = (const bf16x8v*)Af + (size_t)(2 * mt) * NK * 64 + lane;
  const bf16x8v* A1 = A0 + (size_t)NK * 64;
  const bf16x8v* B0 = (const bf16x8v*)Wf + (size_t)(2 * nt) * NK * 64 + lane;
  const bf16x8v* B1 = B0 + (size_t)NK * 64;

  f32x4v acc00 = {0.f, 0.f, 0.f, 0.f};
  f32x4v acc01 = {0.f, 0.f, 0.f, 0.f};
  f32x4v acc10 = {0.f, 0.f, 0.f, 0.f};
  f32x4v acc11 = {0.f, 0.f, 0.f, 0.f};

#pragma unroll 4
  for (int k32 = 0; k32 < NK; ++k32) {
    bf16x8v a0 = A0[(size_t)k32 * 64];
    bf16x8v a1 = A1[(size_t)k32 * 64];
    bf16x8v w0 = B0[(size_t)k32 * 64];
    bf16x8v w1 = B1[(size_t)k32 * 64];
    acc00 = __builtin_amdgcn_mfma_f32_16x16x32_bf16(a0, w0, acc00, 0, 0, 0);
    acc01 = __builtin_amdgcn_mfma_f32_16x16x32_bf16(a0, w1, acc01, 0, 0, 0);
    acc10 = __builtin_amdgcn_mfma_f32_16x16x32_bf16(a1, w0, acc10, 0, 0, 0);
    acc11 = __builtin_amdgcn_mfma_f32_16x16x32_bf16(a1, w1, acc11, 0, 0, 0);
  }

  // C/D layout (verified m89): col = lane&15, row = (lane>>4)*4 + j
  const int m0 = mt * 32, n0 = nt * 32;
  const int col = lane & 15;
  const int rg = (lane >> 4) * 4;
  const float bv0 = bias[n0 + col];
  const float bv1 = bias[n0 + 16 + col];
#pragma unroll
  for (int j = 0; j < 4; ++j) {
    const int r = rg + j;
    C[(size_t)(m0 + r) * N_ + n0 + col]           = acc00[j] + bv0;
    C[(size_t)(m0 + r) * N_ + n0 + 16 + col]      = acc01[j] + bv1;
    C[(size_t)(m0 + 16 + r) * N_ + n0 + col]      = acc10[j] + bv0;
    C[(size_t)(m0 + 16 + r) * N_ + n0 + 16 + col] = acc11[j] + bv1;
  }
}

// ---------------------------------------------------------------------------
// Kernel 3: in-place row L2 normalization of out (2*B rows of 768).
// ---------------------------------------------------------------------------
__global__ __launch_bounds__(256) void norm_rows_kernel(float* __restrict__ out) {
  const int row = blockIdx.x;  // 0..1023
  float* p = out + (size_t)row * N_;
  const int t = threadIdx.x;
  float x0 = p[t];
  float x1 = p[t + 256];
  float x2 = p[t + 512];
  float s = x0*x0 + x1*x1 + x2*x2;
#pragma unroll
  for (int off = 32; off > 0; off >>= 1) s += __shfl_down(s, off);
  __shared__ float ws[4];
  const int lane = t & 63, wid = t >> 6;
  if (lane == 0) ws[wid] = s;
  __syncthreads();
  float tot = ws[0] + ws[1] + ws[2] + ws[3];
  float inv = 1.0f / fmaxf(sqrtf(tot), 1e-12f);
  p[t]       = x0 * inv;
  p[t + 256] = x1 * inv;
  p[t + 512] = x2 * inv;
}

// ---------------------------------------------------------------------------
extern "C" void kernel_launch(void* const* d_in, const int* in_sizes, int n_in,
                              void* d_out, int out_size, void* d_ws, size_t ws_size,
                              hipStream_t stream) {
  const float* phys  = (const float*)d_in[0];
  const float* proc  = (const float*)d_in[1];
  const float* micro = (const float*)d_in[2];
  const int*   pos   = (const int*)d_in[3];
  const float* W1    = (const float*)d_in[4];
  const float* b1    = (const float*)d_in[5];
  const float* W2    = (const float*)d_in[6];
  const float* b2    = (const float*)d_in[7];
  float* out = (float*)d_out;

  // ws layout (bf16): A1f | A2f | W1f | W2f  (total ~9.4 MB)
  __hip_bfloat16* A1f = (__hip_bfloat16*)d_ws;
  __hip_bfloat16* A2f = A1f + (size_t)32 * NK1 * 512;
  __hip_bfloat16* W1f = A2f + (size_t)32 * NK2 * 512;
  __hip_bfloat16* W2f = W1f + (size_t)48 * NK1 * 512;

  pool_cvt_kernel<<<B_ + CVT_BLOCKS, 192, 0, stream>>>(
      phys, proc, micro, pos, W1, W2, A1f, A2f, W1f, W2f);
  gemm_mfma_kernel<<<2 * (M_ / 32) * (N_ / 32), 64, 0, stream>>>(
      A1f, A2f, W1f, W2f, b1, b2, out);
  norm_rows_kernel<<<2 * B_, 256, 0, stream>>>(out);
}

// Round 3
// 48.158 us; speedup vs baseline: 2.6689x; 1.0586x over previous
//
#include <hip/hip_runtime.h>
#include <hip/hip_bf16.h>

// Problem constants (B,S,H,P) = (512, 256, 768, 32)
#define B_  512
#define S_  256
#define H_  768
#define P_  32
#define K1_ 2304   // 3H
#define K2_ 1536   // 2H
#define N_  768
#define M_  512
#define NK1 72     // K1/32
#define NK2 48     // K2/32
#define CVT_BLOCKS 128

typedef __attribute__((ext_vector_type(8))) short bf16x8v;
typedef __attribute__((ext_vector_type(4))) float f32x4v;

// Fragment buffers (bf16), MFMA 16x16x32 operand order:
//   frag[t16][k32][lane][8]  where lane = kg*16 + r  (r = row-in-16, kg = k-subgroup)
//   element (t, k):  t = t16*16 + r,  k = k32*32 + kg*8 + e   (e = 0..7)
// A-frag rows t = m (batch), W-frag rows t = n (output col); W is stored [n][k]
// which is exactly the B^T-input fragment layout (8 consecutive k per lane).

__device__ inline unsigned short bfb(float x) {
  __hip_bfloat16 h = __float2bfloat16(x);  // RNE
  return *reinterpret_cast<unsigned short*>(&h);
}

// store 4 consecutive-k bf16 values (k % 4 == 0) into frag layout, 8B store
__device__ inline void store4_frag(__hip_bfloat16* __restrict__ buf, int NK,
                                   int m, int k, float4 v) {
  int m16 = m >> 4, mr = m & 15, k32 = k >> 5, kg = (k >> 3) & 3, e = k & 7;
  size_t off = ((size_t)(m16 * NK + k32) * 64 + kg * 16 + mr) * 8 + e;
  ushort4 u;
  u.x = bfb(v.x); u.y = bfb(v.y); u.z = bfb(v.z); u.w = bfb(v.w);
  *reinterpret_cast<ushort4*>(buf + off) = u;
}

// ---------------------------------------------------------------------------
// Kernel 1 (fused):
//   blocks [0, 2B):  (batch, tensor) masked mean-pool + concat -> A-frag bf16.
//                    Positions are ballot-compacted into LDS so the gather
//                    loop is branch-free and unrolled (4 loads in flight).
//   blocks [2B, 2B+CVT_BLOCKS): W1/W2 fp32 -> B-frag bf16 (grid-stride).
// ---------------------------------------------------------------------------
__global__ __launch_bounds__(192) void pool_cvt_kernel(
    const float* __restrict__ phys, const float* __restrict__ proc,
    const float* __restrict__ micro, const int* __restrict__ pos,
    const float* __restrict__ W1, const float* __restrict__ W2,
    __hip_bfloat16* __restrict__ A1f, __hip_bfloat16* __restrict__ A2f,
    __hip_bfloat16* __restrict__ W1f, __hip_bfloat16* __restrict__ W2f) {
  const int t = threadIdx.x;  // 0..191
  const int NPOOL = 2 * B_;
  if (blockIdx.x < NPOOL) {
    const int b   = blockIdx.x >> 1;
    const int sel = blockIdx.x & 1;  // 0 = proc, 1 = micro
    __shared__ int sp[P_];
    __shared__ int scnt;
    if (t < 64) {  // wave 0 compacts valid positions
      int p = (t < P_) ? pos[b * P_ + t] : -1;
      bool valid = (p != -1);
      unsigned long long m = __ballot(valid);
      int pre = __popcll(m & ((1ull << t) - 1ull));
      if (valid) sp[pre] = p;
      if (t == 0) scnt = (int)__popcll(m);
    }
    __syncthreads();
    const int c = scnt;              // >= 1 (drop[:,0] == False)
    const float inv = 1.0f / (float)c;

    const int H4 = H_ / 4;  // 192
    const float* base = (sel == 0) ? proc : micro;
    const float4* srcb = (const float4*)(base + (size_t)b * S_ * H_);

    float4 s = make_float4(0.f, 0.f, 0.f, 0.f);
    int i = 0;
    for (; i + 4 <= c; i += 4) {
      int p0 = sp[i], p1 = sp[i+1], p2 = sp[i+2], p3 = sp[i+3];
      float4 v0 = srcb[(size_t)p0 * H4 + t];
      float4 v1 = srcb[(size_t)p1 * H4 + t];
      float4 v2 = srcb[(size_t)p2 * H4 + t];
      float4 v3 = srcb[(size_t)p3 * H4 + t];
      s.x += v0.x + v1.x + v2.x + v3.x;
      s.y += v0.y + v1.y + v2.y + v3.y;
      s.z += v0.z + v1.z + v2.z + v3.z;
      s.w += v0.w + v1.w + v2.w + v3.w;
    }
    for (; i < c; ++i) {
      float4 v = srcb[(size_t)sp[i] * H4 + t];
      s.x += v.x; s.y += v.y; s.z += v.z; s.w += v.w;
    }
    float4 pooled = make_float4(s.x * inv, s.y * inv, s.z * inv, s.w * inv);
    float4 sent = srcb[t];  // row 0

    const int k = t * 4;
    if (sel == 0) {
      store4_frag(A1f, NK1, b, k,          pooled);
      store4_frag(A1f, NK1, b, k + H_,     sent);
      float4 sph = ((const float4*)(phys + (size_t)b * S_ * H_))[t];
      store4_frag(A1f, NK1, b, k + 2*H_,   sph);
    } else {
      store4_frag(A2f, NK2, b, k,          pooled);
      store4_frag(A2f, NK2, b, k + H_,     sent);
    }
  } else {
    // ---- W conversion: grid-stride over 16B fragment groups ----
    const int NG1 = 48 * NK1 * 64;  // 221184
    const int NG2 = 48 * NK2 * 64;  // 147456
    int tid = (blockIdx.x - NPOOL) * 192 + t;
    const int stride = CVT_BLOCKS * 192;
    for (int g = tid; g < NG1 + NG2; g += stride) {
      const float* W; __hip_bfloat16* Wf; int NK, K, gg;
      if (g < NG1) { W = W1; Wf = W1f; NK = NK1; K = K1_; gg = g; }
      else         { W = W2; Wf = W2f; NK = NK2; K = K2_; gg = g - NG1; }
      int lane = gg & 63;
      int rest = gg >> 6;
      int k32 = rest % NK;
      int n16 = rest / NK;
      int n = n16 * 16 + (lane & 15);
      int k = k32 * 32 + (lane >> 4) * 8;
      const float4* sW = (const float4*)(W + (size_t)n * K + k);
      float4 v0 = sW[0], v1 = sW[1];
      ushort4 u0, u1;
      u0.x = bfb(v0.x); u0.y = bfb(v0.y); u0.z = bfb(v0.z); u0.w = bfb(v0.w);
      u1.x = bfb(v1.x); u1.y = bfb(v1.y); u1.z = bfb(v1.z); u1.w = bfb(v1.w);
      ushort4* d = reinterpret_cast<ushort4*>(Wf + (size_t)gg * 8);
      d[0] = u0; d[1] = u1;
    }
  }
}

// ---------------------------------------------------------------------------
// Kernel 2: dual bf16 MFMA GEMM, no LDS, no barriers.
// One wave per block; each wave owns a 32x32 output tile (2x2 fragments).
// ---------------------------------------------------------------------------
__global__ __launch_bounds__(64) void gemm_mfma_kernel(
    const __hip_bfloat16* __restrict__ A1f, const __hip_bfloat16* __restrict__ A2f,
    const __hip_bfloat16* __restrict__ W1f, const __hip_bfloat16* __restrict__ W2f,
    const float* __restrict__ b1, const float* __restrict__ b2,
    float* __restrict__ out) {
  int bid = blockIdx.x;
  const int TPG = (M_ / 32) * (N_ / 32);  // 16*24 = 384 tiles per GEMM
  const __hip_bfloat16 *Af, *Wf;
  const float* bias; float* C; int NK;
  if (bid < TPG) { Af = A1f; Wf = W1f; bias = b1; C = out;                    NK = NK1; }
  else { bid -= TPG; Af = A2f; Wf = W2f; bias = b2; C = out + (size_t)M_*N_;  NK = NK2; }
  const int mt = bid / (N_ / 32);   // 0..15
  const int nt = bid % (N_ / 32);   // 0..23
  const int lane = threadIdx.x;     // 0..63

  const bf16x8v* A0 = (const bf16x8v*)Af + (size_t)(2 * mt) * NK * 64 + lane;
  const bf16x8v* A1 = A0 + (size_t)NK * 64;
  const bf16x8v* B0 = (const bf16x8v*)Wf + (size_t)(2 * nt) * NK * 64 + lane;
  const bf16x8v* B1 = B0 + (size_t)NK * 64;

  f32x4v acc00 = {0.f, 0.f, 0.f, 0.f};
  f32x4v acc01 = {0.f, 0.f, 0.f, 0.f};
  f32x4v acc10 = {0.f, 0.f, 0.f, 0.f};
  f32x4v acc11 = {0.f, 0.f, 0.f, 0.f};

#pragma unroll 4
  for (int k32 = 0; k32 < NK; ++k32) {
    bf16x8v a0 = A0[(size_t)k32 * 64];
    bf16x8v a1 = A1[(size_t)k32 * 64];
    bf16x8v w0 = B0[(size_t)k32 * 64];
    bf16x8v w1 = B1[(size_t)k32 * 64];
    acc00 = __builtin_amdgcn_mfma_f32_16x16x32_bf16(a0, w0, acc00, 0, 0, 0);
    acc01 = __builtin_amdgcn_mfma_f32_16x16x32_bf16(a0, w1, acc01, 0, 0, 0);
    acc10 = __builtin_amdgcn_mfma_f32_16x16x32_bf16(a1, w0, acc10, 0, 0, 0);
    acc11 = __builtin_amdgcn_mfma_f32_16x16x32_bf16(a1, w1, acc11, 0, 0, 0);
  }

  // C/D layout: col = lane&15, row = (lane>>4)*4 + j
  const int m0 = mt * 32, n0 = nt * 32;
  const int col = lane & 15;
  const int rg = (lane >> 4) * 4;
  const float bv0 = bias[n0 + col];
  const float bv1 = bias[n0 + 16 + col];
#pragma unroll
  for (int j = 0; j < 4; ++j) {
    const int r = rg + j;
    C[(size_t)(m0 + r) * N_ + n0 + col]           = acc00[j] + bv0;
    C[(size_t)(m0 + r) * N_ + n0 + 16 + col]      = acc01[j] + bv1;
    C[(size_t)(m0 + 16 + r) * N_ + n0 + col]      = acc10[j] + bv0;
    C[(size_t)(m0 + 16 + r) * N_ + n0 + 16 + col] = acc11[j] + bv1;
  }
}

// ---------------------------------------------------------------------------
// Kernel 3: in-place row L2 normalization of out (2*B rows of 768).
// ---------------------------------------------------------------------------
__global__ __launch_bounds__(256) void norm_rows_kernel(float* __restrict__ out) {
  const int row = blockIdx.x;  // 0..1023
  float* p = out + (size_t)row * N_;
  const int t = threadIdx.x;
  float x0 = p[t];
  float x1 = p[t + 256];
  float x2 = p[t + 512];
  float s = x0*x0 + x1*x1 + x2*x2;
#pragma unroll
  for (int off = 32; off > 0; off >>= 1) s += __shfl_down(s, off);
  __shared__ float ws[4];
  const int lane = t & 63, wid = t >> 6;
  if (lane == 0) ws[wid] = s;
  __syncthreads();
  float tot = ws[0] + ws[1] + ws[2] + ws[3];
  float inv = 1.0f / fmaxf(sqrtf(tot), 1e-12f);
  p[t]       = x0 * inv;
  p[t + 256] = x1 * inv;
  p[t + 512] = x2 * inv;
}

// ---------------------------------------------------------------------------
extern "C" void kernel_launch(void* const* d_in, const int* in_sizes, int n_in,
                              void* d_out, int out_size, void* d_ws, size_t ws_size,
                              hipStream_t stream) {
  const float* phys  = (const float*)d_in[0];
  const float* proc  = (const float*)d_in[1];
  const float* micro = (const float*)d_in[2];
  const int*   pos   = (const int*)d_in[3];
  const float* W1    = (const float*)d_in[4];
  const float* b1    = (const float*)d_in[5];
  const float* W2    = (const float*)d_in[6];
  const float* b2    = (const float*)d_in[7];
  float* out = (float*)d_out;

  // ws layout (bf16): A1f | A2f | W1f | W2f  (total ~9.4 MB)
  __hip_bfloat16* A1f = (__hip_bfloat16*)d_ws;
  __hip_bfloat16* A2f = A1f + (size_t)32 * NK1 * 512;
  __hip_bfloat16* W1f = A2f + (size_t)32 * NK2 * 512;
  __hip_bfloat16* W2f = W1f + (size_t)48 * NK1 * 512;

  pool_cvt_kernel<<<2 * B_ + CVT_BLOCKS, 192, 0, stream>>>(
      phys, proc, micro, pos, W1, W2, A1f, A2f, W1f, W2f);
  gemm_mfma_kernel<<<2 * (M_ / 32) * (N_ / 32), 64, 0, stream>>>(
      A1f, A2f, W1f, W2f, b1, b2, out);
  norm_rows_kernel<<<2 * B_, 256, 0, stream>>>(out);
}